// Round 1
// baseline (3591.784 us; speedup 1.0000x reference)
//
#include <hip/hip_runtime.h>
#include <math.h>

#define Hdim 2048
#define Ldim 256
#define NBLK 256
#define TPB  1024
#define JPB  8      // h-elements per block (Hdim / NBLK)

// workspace layout (float offsets)
#define WS_U    0        // 2048   : u[k] = Wp[:,2:]*consts + b_pre
#define WS_H    2048     // 2*2048 : double-buffered h
#define WS_APK  6144     // 6144   : pk coefficient  (W_ih @ Wp[:,0])
#define WS_ATP  12288    // 6144   : tp coefficient  (W_ih @ Wp[:,1])
#define WS_CVT  18432    // 6144   : const part of gi (W_ih @ u + b_ih)
#define WS_PP   24576    // 2*256  : double-buffered per-block pred partials
#define WS_CNT  25088    // 1 uint : grid barrier counter

// ---------------- prep 1: u vector, h0 copy, counter reset, out[0] ----------
__global__ void prep1(const float* __restrict__ Wp, const float* __restrict__ bpre,
                      const float* __restrict__ dose, const float* __restrict__ route,
                      const float* __restrict__ emb, const int* __restrict__ pat,
                      const float* __restrict__ smiles, const float* __restrict__ pkdata,
                      float* __restrict__ ws, float* __restrict__ out)
{
    int tid = threadIdx.x;
    float d = dose[0], rt = route[0];
    int p = pat[0];
    float e0 = emb[p*3+0], e1 = emb[p*3+1], e2 = emb[p*3+2];
    for (int i = tid; i < Hdim; i += 256) {
        const float* w = Wp + i*7;
        ws[WS_U + i] = d*w[2] + e0*w[3] + e1*w[4] + e2*w[5] + rt*w[6] + bpre[i];
        ws[WS_H + i] = smiles[i];          // h buffer 0 = h0
    }
    if (tid == 0) {
        *(unsigned int*)(ws + WS_CNT) = 0u;
        out[0] = pkdata[0];
    }
}

// ---------------- prep 2: fold W_ih through W_pre (3 matvecs) ---------------
// one wave per row of W_ih (6144 rows)
__global__ void prep2(const float* __restrict__ Wih, const float* __restrict__ Wp,
                      const float* __restrict__ bih, float* __restrict__ ws)
{
    int row  = blockIdx.x*4 + (threadIdx.x >> 6);
    int lane = threadIdx.x & 63;
    const float* wr = Wih + (size_t)row * Hdim;
    const float* u  = ws + WS_U;
    float s0 = 0.f, s1 = 0.f, s2 = 0.f;
    #pragma unroll
    for (int c = 0; c < 8; ++c) {
        int col = c*256 + lane*4;
        float4 wv = *(const float4*)(wr + col);
        float4 uv = *(const float4*)(u + col);
        s0 += wv.x*Wp[(col+0)*7+0] + wv.y*Wp[(col+1)*7+0]
            + wv.z*Wp[(col+2)*7+0] + wv.w*Wp[(col+3)*7+0];
        s1 += wv.x*Wp[(col+0)*7+1] + wv.y*Wp[(col+1)*7+1]
            + wv.z*Wp[(col+2)*7+1] + wv.w*Wp[(col+3)*7+1];
        s2 += wv.x*uv.x + wv.y*uv.y + wv.z*uv.z + wv.w*uv.w;
    }
    #pragma unroll
    for (int off = 32; off >= 1; off >>= 1) {
        s0 += __shfl_down(s0, off, 64);
        s1 += __shfl_down(s1, off, 64);
        s2 += __shfl_down(s2, off, 64);
    }
    if (lane == 0) {
        ws[WS_APK + row] = s0;
        ws[WS_ATP + row] = s1;
        ws[WS_CVT + row] = s2 + bih[row];
    }
}

// ---------------- main persistent kernel ------------------------------------
// 256 blocks x 1024 threads, 1 block/CU. Block b owns h[j], j = b*8..b*8+7.
// W_hh rows j (reset), j+H (update), j+2H (new) live in registers.
__global__ __launch_bounds__(TPB, 4) void gru_main(
    const float* __restrict__ Whh, const float* __restrict__ bhh,
    const float* __restrict__ Wout, const float* __restrict__ bout,
    const float* __restrict__ tps,  const float* __restrict__ pkdata,
    const int*   __restrict__ tf,   const float* __restrict__ smiles,
    float* __restrict__ ws, float* __restrict__ out)
{
    const int b    = blockIdx.x;
    const int tid  = threadIdx.x;
    const int g    = tid >> 7;      // 0..7 : which j this group handles
    const int k    = tid & 127;     // 0..127 : column group within j
    const int wv   = tid >> 6;      // wave id 0..15
    const int lane = tid & 63;
    const int j    = b*JPB + g;

    __shared__ float sred[16][4];
    __shared__ float spp[JPB];
    __shared__ float sPk;
    __shared__ float s_tp[Ldim];
    __shared__ float s_pkd[Ldim];
    __shared__ int   s_tf[Ldim];

    float* hbuf  = ws + WS_H;
    float* ppbuf = ws + WS_PP;
    unsigned int* cnt = (unsigned int*)(ws + WS_CNT);

    // stage small per-step scalars into LDS (off the critical path)
    for (int i = tid; i < Ldim; i += TPB) {
        s_tp[i]  = tps[i];
        s_pkd[i] = pkdata[i];
        s_tf[i]  = tf[i];
    }

    // W_hh rows -> registers (48 VGPRs), coalesced float4 loads
    float4 w[3][4];
    #pragma unroll
    for (int r = 0; r < 3; ++r) {
        const float* base = Whh + (size_t)(j + r*Hdim) * Hdim;
        #pragma unroll
        for (int c = 0; c < 4; ++c)
            w[r][c] = *(const float4*)(base + c*512 + k*4);
    }

    // leader-only constants (k == 0): gi coefficients, biases, W_out, h_prev
    float apk_r=0, apk_z=0, apk_n=0, atp_r=0, atp_z=0, atp_n=0,
          cvt_r=0, cvt_z=0, cvt_n=0, br=0, bz=0, bn=0, wj=0, hprev=0;
    if (k == 0) {
        apk_r = ws[WS_APK + j]; apk_z = ws[WS_APK + j + Hdim]; apk_n = ws[WS_APK + j + 2*Hdim];
        atp_r = ws[WS_ATP + j]; atp_z = ws[WS_ATP + j + Hdim]; atp_n = ws[WS_ATP + j + 2*Hdim];
        cvt_r = ws[WS_CVT + j]; cvt_z = ws[WS_CVT + j + Hdim]; cvt_n = ws[WS_CVT + j + 2*Hdim];
        br = bhh[j]; bz = bhh[j + Hdim]; bn = bhh[j + 2*Hdim];
        wj = Wout[j];
        hprev = smiles[j];
    }
    const float bo = bout[0];
    __syncthreads();

    for (int t = 0; t < Ldim - 1; ++t) {
        const float* hc = hbuf + (t & 1) * Hdim;
        float*       hn = hbuf + ((t + 1) & 1) * Hdim;

        // partial dots: 3 gate rows x 16 columns per thread
        float pr = 0.f, pz = 0.f, pn = 0.f;
        #pragma unroll
        for (int c = 0; c < 4; ++c) {
            float4 hv4 = *(const float4*)(hc + c*512 + k*4);
            pr += w[0][c].x*hv4.x + w[0][c].y*hv4.y + w[0][c].z*hv4.z + w[0][c].w*hv4.w;
            pz += w[1][c].x*hv4.x + w[1][c].y*hv4.y + w[1][c].z*hv4.z + w[1][c].w*hv4.w;
            pn += w[2][c].x*hv4.x + w[2][c].y*hv4.y + w[2][c].z*hv4.z + w[2][c].w*hv4.w;
        }
        #pragma unroll
        for (int off = 32; off >= 1; off >>= 1) {
            pr += __shfl_down(pr, off, 64);
            pz += __shfl_down(pz, off, 64);
            pn += __shfl_down(pn, off, 64);
        }
        if (lane == 0) { sred[wv][0] = pr; sred[wv][1] = pz; sred[wv][2] = pn; }
        __syncthreads();

        // wave 0: reduce previous step's pred partials -> pk for this step
        if (wv == 0) {
            const float* pp = ppbuf + ((t & 1) ^ 1) * NBLK;
            float4 pv = *(const float4*)(pp + lane*4);
            float s = pv.x + pv.y + pv.z + pv.w;
            #pragma unroll
            for (int off = 32; off >= 1; off >>= 1) s += __shfl_down(s, off, 64);
            if (lane == 0) {
                float pred = s + bo;                 // pred_{t-1}
                float pk;
                if (t == 0) pk = s_pkd[0];
                else        pk = (s_tf[t] == 1) ? pred : s_pkd[t];
                sPk = pk;
                if (b == 0 && t > 0) out[t] = pred;  // outputs[t] = pred_{t-1}
            }
        }
        __syncthreads();

        // leaders: gates + h update
        if (k == 0) {
            float dotr = sred[2*g][0] + sred[2*g+1][0];
            float dotz = sred[2*g][1] + sred[2*g+1][1];
            float dotn = sred[2*g][2] + sred[2*g+1][2];
            float pk = sPk;
            float tp = s_tp[t];
            float gr  = apk_r*pk + atp_r*tp + cvt_r + dotr + br;
            float gz  = apk_z*pk + atp_z*tp + cvt_z + dotz + bz;
            float gin = apk_n*pk + atp_n*tp + cvt_n;
            float r = 1.0f / (1.0f + expf(-gr));
            float z = 1.0f / (1.0f + expf(-gz));
            float n = tanhf(gin + r*(dotn + bn));
            float hvnew = (1.0f - z)*n + z*hprev;
            hprev = hvnew;
            __hip_atomic_store(hn + j, hvnew, __ATOMIC_RELAXED, __HIP_MEMORY_SCOPE_AGENT);
            spp[g] = wj * hvnew;
        }
        __syncthreads();

        // thread 0: block pred partial, then grid barrier (monotonic counter)
        if (tid == 0) {
            float s = 0.f;
            #pragma unroll
            for (int q = 0; q < JPB; ++q) s += spp[q];
            __hip_atomic_store(ppbuf + (t & 1)*NBLK + b, s,
                               __ATOMIC_RELAXED, __HIP_MEMORY_SCOPE_AGENT);
            __builtin_amdgcn_fence(__ATOMIC_RELEASE, "agent");
            __hip_atomic_fetch_add(cnt, 1u, __ATOMIC_RELAXED, __HIP_MEMORY_SCOPE_AGENT);
            unsigned int target = (unsigned int)(NBLK * (t + 1));
            while (__hip_atomic_load(cnt, __ATOMIC_RELAXED, __HIP_MEMORY_SCOPE_AGENT) < target)
                __builtin_amdgcn_s_sleep(1);
            __builtin_amdgcn_fence(__ATOMIC_ACQUIRE, "agent");
        }
        __syncthreads();
    }

    // final prediction -> out[255]
    if (b == 0 && wv == 0) {
        const float* pp = ppbuf + ((Ldim - 2) & 1) * NBLK;
        float4 pv = *(const float4*)(pp + lane*4);
        float s = pv.x + pv.y + pv.z + pv.w;
        #pragma unroll
        for (int off = 32; off >= 1; off >>= 1) s += __shfl_down(s, off, 64);
        if (lane == 0) out[Ldim - 1] = s + bo;
    }
}

extern "C" void kernel_launch(void* const* d_in, const int* in_sizes, int n_in,
                              void* d_out, int out_size, void* d_ws, size_t ws_size,
                              hipStream_t stream)
{
    const float* tps    = (const float*)d_in[0];   // timepoints (256,1)
    const float* pkdata = (const float*)d_in[1];   // pk_data (256,1)
    // d_in[2] = input_len (unused, static 256)
    const int*   pat    = (const int*)  d_in[3];   // emb_patient
    const float* route  = (const float*)d_in[4];   // drug_route (1,)
    const float* dose   = (const float*)d_in[5];   // dose (1,)
    const float* smiles = (const float*)d_in[6];   // (1, 2048)
    const int*   tfm    = (const int*)  d_in[7];   // tf_mask (256,)
    const float* emb    = (const float*)d_in[8];   // emb_table (8,3)
    const float* Wp     = (const float*)d_in[9];   // W_pre (2048,7)
    const float* bpre   = (const float*)d_in[10];  // b_pre (2048,)
    const float* Wih    = (const float*)d_in[11];  // W_ih (6144,2048)
    const float* Whh    = (const float*)d_in[12];  // W_hh (6144,2048)
    const float* bih    = (const float*)d_in[13];  // b_ih (6144,)
    const float* bhh    = (const float*)d_in[14];  // b_hh (6144,)
    const float* Wout   = (const float*)d_in[15];  // W_out (1,2048)
    const float* bout   = (const float*)d_in[16];  // b_out (1,)
    float* out = (float*)d_out;
    float* ws  = (float*)d_ws;

    hipLaunchKernelGGL(prep1, dim3(1), dim3(256), 0, stream,
                       Wp, bpre, dose, route, emb, pat, smiles, pkdata, ws, out);
    hipLaunchKernelGGL(prep2, dim3(1536), dim3(256), 0, stream,
                       Wih, Wp, bih, ws);
    hipLaunchKernelGGL(gru_main, dim3(NBLK), dim3(TPB), 0, stream,
                       Whh, bhh, Wout, bout, tps, pkdata, tfm, smiles, ws, out);
}

// Round 2
// 2888.736 us; speedup vs baseline: 1.2434x; 1.2434x over previous
//
#include <hip/hip_runtime.h>
#include <math.h>

#define Hdim 2048
#define Ldim 256
#define NBLK 256
#define TPB  1024
#define JPB  8      // h-elements per block (Hdim / NBLK)

// workspace layout (float offsets)
#define WS_U    0        // 2048   : u[k] = Wp[:,2:]*consts + b_pre
#define WS_H    2048     // 2*2048 : double-buffered h
#define WS_APK  6144     // 6144   : pk coefficient  (W_ih @ Wp[:,0])
#define WS_ATP  12288    // 6144   : tp coefficient  (W_ih @ Wp[:,1])
#define WS_CVT  18432    // 6144   : const part of gi (W_ih @ u + b_ih)
#define WS_PP   24576    // 2*256  : double-buffered per-block pred partials
#define WS_SEQ  25088    // 256 ints : per-block monotonic step flags

// ---------------- prep 1: u vector, h0 copy, flag reset, out[0] -------------
__global__ void prep1(const float* __restrict__ Wp, const float* __restrict__ bpre,
                      const float* __restrict__ dose, const float* __restrict__ route,
                      const float* __restrict__ emb, const int* __restrict__ pat,
                      const float* __restrict__ smiles, const float* __restrict__ pkdata,
                      float* __restrict__ ws, float* __restrict__ out)
{
    int tid = threadIdx.x;
    float d = dose[0], rt = route[0];
    int p = pat[0];
    float e0 = emb[p*3+0], e1 = emb[p*3+1], e2 = emb[p*3+2];
    for (int i = tid; i < Hdim; i += 256) {
        const float* w = Wp + i*7;
        ws[WS_U + i] = d*w[2] + e0*w[3] + e1*w[4] + e2*w[5] + rt*w[6] + bpre[i];
        ws[WS_H + i] = smiles[i];          // h buffer 0 = h0
    }
    // zero the 256 per-block flags and both pred-partial buffers
    ((int*)(ws + WS_SEQ))[tid] = 0;
    ws[WS_PP + tid] = 0.0f;
    ws[WS_PP + NBLK + tid] = 0.0f;
    if (tid == 0) out[0] = pkdata[0];
}

// ---------------- prep 2: fold W_ih through W_pre (3 matvecs) ---------------
// one wave per row of W_ih (6144 rows)
__global__ void prep2(const float* __restrict__ Wih, const float* __restrict__ Wp,
                      const float* __restrict__ bih, float* __restrict__ ws)
{
    int row  = blockIdx.x*4 + (threadIdx.x >> 6);
    int lane = threadIdx.x & 63;
    const float* wr = Wih + (size_t)row * Hdim;
    const float* u  = ws + WS_U;
    float s0 = 0.f, s1 = 0.f, s2 = 0.f;
    #pragma unroll
    for (int c = 0; c < 8; ++c) {
        int col = c*256 + lane*4;
        float4 wv = *(const float4*)(wr + col);
        float4 uv = *(const float4*)(u + col);
        s0 += wv.x*Wp[(col+0)*7+0] + wv.y*Wp[(col+1)*7+0]
            + wv.z*Wp[(col+2)*7+0] + wv.w*Wp[(col+3)*7+0];
        s1 += wv.x*Wp[(col+0)*7+1] + wv.y*Wp[(col+1)*7+1]
            + wv.z*Wp[(col+2)*7+1] + wv.w*Wp[(col+3)*7+1];
        s2 += wv.x*uv.x + wv.y*uv.y + wv.z*uv.z + wv.w*uv.w;
    }
    #pragma unroll
    for (int off = 32; off >= 1; off >>= 1) {
        s0 += __shfl_down(s0, off, 64);
        s1 += __shfl_down(s1, off, 64);
        s2 += __shfl_down(s2, off, 64);
    }
    if (lane == 0) {
        ws[WS_APK + row] = s0;
        ws[WS_ATP + row] = s1;
        ws[WS_CVT + row] = s2 + bih[row];
    }
}

// ---------------- main persistent kernel ------------------------------------
// 256 blocks x 1024 threads, 1 block/CU. Block b owns h[j], j = b*8..b*8+7.
// Sync: per-block monotonic seq flags (NO atomic RMW, no shared counter).
__global__ __launch_bounds__(TPB, 4) void gru_main(
    const float* __restrict__ Whh, const float* __restrict__ bhh,
    const float* __restrict__ Wout, const float* __restrict__ bout,
    const float* __restrict__ tps,  const float* __restrict__ pkdata,
    const int*   __restrict__ tf,   const float* __restrict__ smiles,
    float* __restrict__ ws, float* __restrict__ out)
{
    const int b    = blockIdx.x;
    const int tid  = threadIdx.x;
    const int g    = tid >> 7;      // 0..7 : which j this group handles
    const int k    = tid & 127;     // 0..127 : column group within j
    const int wv   = tid >> 6;      // wave id 0..15
    const int lane = tid & 63;
    const int j    = b*JPB + g;

    __shared__ float sred[16][4];
    __shared__ float spp[JPB];
    __shared__ float sh[JPB];
    __shared__ float sPk;
    __shared__ float s_tp[Ldim];
    __shared__ float s_pkd[Ldim];
    __shared__ int   s_tf[Ldim];

    float* hbuf  = ws + WS_H;
    float* ppbuf = ws + WS_PP;
    int*   seqp  = (int*)(ws + WS_SEQ);

    // stage small per-step scalars into LDS (off the critical path)
    for (int i = tid; i < Ldim; i += TPB) {
        s_tp[i]  = tps[i];
        s_pkd[i] = pkdata[i];
        s_tf[i]  = tf[i];
    }

    // W_hh rows -> registers (48 VGPRs), coalesced float4 loads
    float4 w[3][4];
    #pragma unroll
    for (int r = 0; r < 3; ++r) {
        const float* base = Whh + (size_t)(j + r*Hdim) * Hdim;
        #pragma unroll
        for (int c = 0; c < 4; ++c)
            w[r][c] = *(const float4*)(base + c*512 + k*4);
    }

    // leader-only constants (k == 0)
    float apk_r=0, apk_z=0, apk_n=0, atp_r=0, atp_z=0, atp_n=0,
          cvt_r=0, cvt_z=0, cvt_n=0, br=0, bz=0, bn=0, wj=0, hprev=0;
    if (k == 0) {
        apk_r = ws[WS_APK + j]; apk_z = ws[WS_APK + j + Hdim]; apk_n = ws[WS_APK + j + 2*Hdim];
        atp_r = ws[WS_ATP + j]; atp_z = ws[WS_ATP + j + Hdim]; atp_n = ws[WS_ATP + j + 2*Hdim];
        cvt_r = ws[WS_CVT + j]; cvt_z = ws[WS_CVT + j + Hdim]; cvt_n = ws[WS_CVT + j + 2*Hdim];
        br = bhh[j]; bz = bhh[j + Hdim]; bn = bhh[j + 2*Hdim];
        wj = Wout[j];
        hprev = smiles[j];
    }
    const float bo = bout[0];
    __syncthreads();

    for (int t = 0; t < Ldim - 1; ++t) {
        const int pr_ = t & 1;        // read parity (h_t, pred partials from t-1)
        const int pw_ = pr_ ^ 1;      // write parity (h_{t+1}, pred partials t)
        const float* hc = hbuf + pr_ * Hdim;

        // partial dots: 3 gate rows x 16 columns per thread
        float pr = 0.f, pz = 0.f, pn = 0.f;
        #pragma unroll
        for (int c = 0; c < 4; ++c) {
            float4 hv4 = *(const float4*)(hc + c*512 + k*4);
            pr += w[0][c].x*hv4.x + w[0][c].y*hv4.y + w[0][c].z*hv4.z + w[0][c].w*hv4.w;
            pz += w[1][c].x*hv4.x + w[1][c].y*hv4.y + w[1][c].z*hv4.z + w[1][c].w*hv4.w;
            pn += w[2][c].x*hv4.x + w[2][c].y*hv4.y + w[2][c].z*hv4.z + w[2][c].w*hv4.w;
        }
        #pragma unroll
        for (int off = 32; off >= 1; off >>= 1) {
            pr += __shfl_down(pr, off, 64);
            pz += __shfl_down(pz, off, 64);
            pn += __shfl_down(pn, off, 64);
        }
        if (lane == 0) { sred[wv][0] = pr; sred[wv][1] = pz; sred[wv][2] = pn; }

        // wave 0: reduce previous step's pred partials -> pk for this step
        if (wv == 0) {
            float4 pv = *(const float4*)(ppbuf + pr_ * NBLK + lane*4);
            float s = pv.x + pv.y + pv.z + pv.w;
            #pragma unroll
            for (int off = 32; off >= 1; off >>= 1) s += __shfl_down(s, off, 64);
            if (lane == 0) {
                float pred = s + bo;                 // pred_{t-1}
                float pk;
                if (t == 0) pk = s_pkd[0];
                else        pk = (s_tf[t] == 1) ? pred : s_pkd[t];
                sPk = pk;
                if (b == 0 && t > 0) out[t] = pred;  // outputs[t] = pred_{t-1}
            }
        }
        __syncthreads();

        // leaders: gates + h update
        if (k == 0) {
            float dotr = sred[2*g][0] + sred[2*g+1][0];
            float dotz = sred[2*g][1] + sred[2*g+1][1];
            float dotn = sred[2*g][2] + sred[2*g+1][2];
            float pk = sPk;
            float tp = s_tp[t];
            float gr  = apk_r*pk + atp_r*tp + cvt_r + dotr + br;
            float gz  = apk_z*pk + atp_z*tp + cvt_z + dotz + bz;
            float gin = apk_n*pk + atp_n*tp + cvt_n;
            float r = 1.0f / (1.0f + expf(-gr));
            float z = 1.0f / (1.0f + expf(-gz));
            float n = tanhf(gin + r*(dotn + bn));
            float hvnew = (1.0f - z)*n + z*hprev;
            hprev = hvnew;
            sh[g]  = hvnew;
            spp[g] = wj * hvnew;
        }
        __syncthreads();

        // wave 0: publish h segment + pred partial, set flag, poll peers
        if (wv == 0) {
            if (lane == 0) {
                float* hd = hbuf + pw_ * Hdim + b * JPB;
                #pragma unroll
                for (int q = 0; q < JPB; ++q)
                    __hip_atomic_store(hd + q, sh[q],
                                       __ATOMIC_RELAXED, __HIP_MEMORY_SCOPE_AGENT);
                float s = 0.f;
                #pragma unroll
                for (int q = 0; q < JPB; ++q) s += spp[q];
                __hip_atomic_store(ppbuf + pw_ * NBLK + b, s,
                                   __ATOMIC_RELAXED, __HIP_MEMORY_SCOPE_AGENT);
                __builtin_amdgcn_fence(__ATOMIC_RELEASE, "agent");
                __hip_atomic_store(seqp + b, t + 1,
                                   __ATOMIC_RELAXED, __HIP_MEMORY_SCOPE_AGENT);
            }
            const int target = t + 1;
            const int* sp = seqp + lane * 4;
            for (;;) {
                int a0 = __hip_atomic_load(sp + 0, __ATOMIC_RELAXED, __HIP_MEMORY_SCOPE_AGENT);
                int a1 = __hip_atomic_load(sp + 1, __ATOMIC_RELAXED, __HIP_MEMORY_SCOPE_AGENT);
                int a2 = __hip_atomic_load(sp + 2, __ATOMIC_RELAXED, __HIP_MEMORY_SCOPE_AGENT);
                int a3 = __hip_atomic_load(sp + 3, __ATOMIC_RELAXED, __HIP_MEMORY_SCOPE_AGENT);
                int ok = (a0 >= target) && (a1 >= target) && (a2 >= target) && (a3 >= target);
                if (__all(ok)) break;
            }
            __builtin_amdgcn_fence(__ATOMIC_ACQUIRE, "agent");
        }
        __syncthreads();
    }

    // final prediction -> out[255] (written at t=254 into parity 1)
    if (b == 0 && wv == 0) {
        float4 pv = *(const float4*)(ppbuf + ((Ldim - 1) & 1) * NBLK + lane*4);
        float s = pv.x + pv.y + pv.z + pv.w;
        #pragma unroll
        for (int off = 32; off >= 1; off >>= 1) s += __shfl_down(s, off, 64);
        if (lane == 0) out[Ldim - 1] = s + bo;
    }
}

extern "C" void kernel_launch(void* const* d_in, const int* in_sizes, int n_in,
                              void* d_out, int out_size, void* d_ws, size_t ws_size,
                              hipStream_t stream)
{
    const float* tps    = (const float*)d_in[0];   // timepoints (256,1)
    const float* pkdata = (const float*)d_in[1];   // pk_data (256,1)
    // d_in[2] = input_len (unused, static 256)
    const int*   pat    = (const int*)  d_in[3];   // emb_patient
    const float* route  = (const float*)d_in[4];   // drug_route (1,)
    const float* dose   = (const float*)d_in[5];   // dose (1,)
    const float* smiles = (const float*)d_in[6];   // (1, 2048)
    const int*   tfm    = (const int*)  d_in[7];   // tf_mask (256,)
    const float* emb    = (const float*)d_in[8];   // emb_table (8,3)
    const float* Wp     = (const float*)d_in[9];   // W_pre (2048,7)
    const float* bpre   = (const float*)d_in[10];  // b_pre (2048,)
    const float* Wih    = (const float*)d_in[11];  // W_ih (6144,2048)
    const float* Whh    = (const float*)d_in[12];  // W_hh (6144,2048)
    const float* bih    = (const float*)d_in[13];  // b_ih (6144,)
    const float* bhh    = (const float*)d_in[14];  // b_hh (6144,)
    const float* Wout   = (const float*)d_in[15];  // W_out (1,2048)
    const float* bout   = (const float*)d_in[16];  // b_out (1,)
    float* out = (float*)d_out;
    float* ws  = (float*)d_ws;

    hipLaunchKernelGGL(prep1, dim3(1), dim3(256), 0, stream,
                       Wp, bpre, dose, route, emb, pat, smiles, pkdata, ws, out);
    hipLaunchKernelGGL(prep2, dim3(1536), dim3(256), 0, stream,
                       Wih, Wp, bih, ws);
    hipLaunchKernelGGL(gru_main, dim3(NBLK), dim3(TPB), 0, stream,
                       Whh, bhh, Wout, bout, tps, pkdata, tfm, smiles, ws, out);
}

// Round 3
// 2071.327 us; speedup vs baseline: 1.7340x; 1.3946x over previous
//
#include <hip/hip_runtime.h>
#include <math.h>

#define Hdim 2048
#define Ldim 256
#define NBLK 256
#define TPB  1024
#define JPB  8      // h-elements per block (Hdim / NBLK)

// workspace layout (float offsets)
#define WS_U    0        // 2048 : u[k] = Wp[:,2:]*consts + b_pre
#define WS_HP   2048     // 8192 : 2 parities x 2048 pairs x 2 words (tagged h)
#define WS_APK  10240    // 6144 : pk coefficient  (W_ih @ Wp[:,0])
#define WS_ATP  16384    // 6144 : tp coefficient  (W_ih @ Wp[:,1])
#define WS_CVT  22528    // 6144 : const part of gi (W_ih @ u + b_ih)

// ---------------- prep 1: u vector, tagged h0 pairs, out[0] -----------------
__global__ void prep1(const float* __restrict__ Wp, const float* __restrict__ bpre,
                      const float* __restrict__ dose, const float* __restrict__ route,
                      const float* __restrict__ emb, const int* __restrict__ pat,
                      const float* __restrict__ smiles, const float* __restrict__ pkdata,
                      float* __restrict__ ws, float* __restrict__ out)
{
    int tid = threadIdx.x;
    float d = dose[0], rt = route[0];
    int p = pat[0];
    float e0 = emb[p*3+0], e1 = emb[p*3+1], e2 = emb[p*3+2];
    unsigned long long* hp0 = (unsigned long long*)(ws + WS_HP);  // parity 0
    for (int i = tid; i < Hdim; i += 256) {
        const float* w = Wp + i*7;
        ws[WS_U + i] = d*w[2] + e0*w[3] + e1*w[4] + e2*w[5] + rt*w[6] + bpre[i];
        union { float f; unsigned u; } cv; cv.f = smiles[i];
        hp0[i] = (unsigned long long)cv.u;      // tag 0 in high word, h0 in low
    }
    if (tid == 0) out[0] = pkdata[0];
}

// ---------------- prep 2: fold W_ih through W_pre (3 matvecs) ---------------
__global__ void prep2(const float* __restrict__ Wih, const float* __restrict__ Wp,
                      const float* __restrict__ bih, float* __restrict__ ws)
{
    int row  = blockIdx.x*4 + (threadIdx.x >> 6);
    int lane = threadIdx.x & 63;
    const float* wr = Wih + (size_t)row * Hdim;
    const float* u  = ws + WS_U;
    float s0 = 0.f, s1 = 0.f, s2 = 0.f;
    #pragma unroll
    for (int c = 0; c < 8; ++c) {
        int col = c*256 + lane*4;
        float4 wv = *(const float4*)(wr + col);
        float4 uv = *(const float4*)(u + col);
        s0 += wv.x*Wp[(col+0)*7+0] + wv.y*Wp[(col+1)*7+0]
            + wv.z*Wp[(col+2)*7+0] + wv.w*Wp[(col+3)*7+0];
        s1 += wv.x*Wp[(col+0)*7+1] + wv.y*Wp[(col+1)*7+1]
            + wv.z*Wp[(col+2)*7+1] + wv.w*Wp[(col+3)*7+1];
        s2 += wv.x*uv.x + wv.y*uv.y + wv.z*uv.z + wv.w*uv.w;
    }
    #pragma unroll
    for (int off = 32; off >= 1; off >>= 1) {
        s0 += __shfl_down(s0, off, 64);
        s1 += __shfl_down(s1, off, 64);
        s2 += __shfl_down(s2, off, 64);
    }
    if (lane == 0) {
        ws[WS_APK + row] = s0;
        ws[WS_ATP + row] = s1;
        ws[WS_CVT + row] = s2 + bih[row];
    }
}

// ---------------- main persistent kernel ------------------------------------
// 256 blocks x 1024 threads, 1 block/CU. Block b owns h[j], j = b*8..b*8+7.
// Sync: tagged (step,value) 64-bit pairs — data IS the flag. No fences.
__global__ __launch_bounds__(TPB, 4) void gru_main(
    const float* __restrict__ Whh, const float* __restrict__ bhh,
    const float* __restrict__ Wout, const float* __restrict__ bout,
    const float* __restrict__ tps,  const float* __restrict__ pkdata,
    const int*   __restrict__ tf,   const float* __restrict__ smiles,
    float* __restrict__ ws, float* __restrict__ out)
{
    const int b    = blockIdx.x;
    const int tid  = threadIdx.x;
    const int g    = tid >> 7;      // 0..7 : which j this group handles
    const int k    = tid & 127;     // 0..127 : column group within j
    const int wv   = tid >> 6;      // wave id 0..15
    const int lane = tid & 63;
    const int j    = b*JPB + g;

    __shared__ float sh_h[Hdim];
    __shared__ float sred[16][3];
    __shared__ float swp[16];
    __shared__ float sPk;
    __shared__ float s_tp[Ldim];
    __shared__ float s_pkd[Ldim];
    __shared__ int   s_tf[Ldim];

    unsigned long long* hp = (unsigned long long*)(ws + WS_HP);

    for (int i = tid; i < Ldim; i += TPB) {
        s_tp[i]  = tps[i];
        s_pkd[i] = pkdata[i];
        s_tf[i]  = tf[i];
    }

    // W_hh rows -> registers (48 VGPRs), coalesced float4 loads
    float4 w[3][4];
    #pragma unroll
    for (int r = 0; r < 3; ++r) {
        const float* base = Whh + (size_t)(j + r*Hdim) * Hdim;
        #pragma unroll
        for (int c = 0; c < 4; ++c)
            w[r][c] = *(const float4*)(base + c*512 + k*4);
    }

    // per-thread W_out slice (for redundant local pred computation)
    const int i0 = tid * 2;
    const float wo0 = Wout[i0], wo1 = Wout[i0 + 1];

    // leader-only constants (k == 0)
    float apk_r=0, apk_z=0, apk_n=0, atp_r=0, atp_z=0, atp_n=0,
          cvt_r=0, cvt_z=0, cvt_n=0, br=0, bz=0, bn=0, hprev=0;
    if (k == 0) {
        apk_r = ws[WS_APK + j]; apk_z = ws[WS_APK + j + Hdim]; apk_n = ws[WS_APK + j + 2*Hdim];
        atp_r = ws[WS_ATP + j]; atp_z = ws[WS_ATP + j + Hdim]; atp_n = ws[WS_ATP + j + 2*Hdim];
        cvt_r = ws[WS_CVT + j]; cvt_z = ws[WS_CVT + j + Hdim]; cvt_n = ws[WS_CVT + j + 2*Hdim];
        br = bhh[j]; bz = bhh[j + Hdim]; bn = bhh[j + 2*Hdim];
        hprev = smiles[j];
    }
    const float bo = bout[0];
    __syncthreads();

    for (int t = 0; t < Ldim - 1; ++t) {
        const int pr_ = t & 1;
        const int pw_ = pr_ ^ 1;
        unsigned long long* hin = hp + pr_ * Hdim;

        // ---- stage: poll own 2 tagged pairs, write to LDS ----
        unsigned long long p0, p1;
        for (;;) {
            p0 = __hip_atomic_load(hin + i0,     __ATOMIC_RELAXED, __HIP_MEMORY_SCOPE_AGENT);
            p1 = __hip_atomic_load(hin + i0 + 1, __ATOMIC_RELAXED, __HIP_MEMORY_SCOPE_AGENT);
            if ((int)(p0 >> 32) >= t && (int)(p1 >> 32) >= t) break;
        }
        union { unsigned u; float f; } c0, c1;
        c0.u = (unsigned)p0; c1.u = (unsigned)p1;
        sh_h[i0]     = c0.f;
        sh_h[i0 + 1] = c1.f;

        // local pred partial (pred_{t-1} = W_out . h_t + b_out)
        float wpart = wo0*c0.f + wo1*c1.f;
        #pragma unroll
        for (int off = 32; off >= 1; off >>= 1) wpart += __shfl_down(wpart, off, 64);
        if (lane == 0) swp[wv] = wpart;
        __syncthreads();                         // B1: h staged

        // ---- dots: 3 gate rows x 16 columns per thread, from LDS ----
        float pr = 0.f, pz = 0.f, pn = 0.f;
        #pragma unroll
        for (int c = 0; c < 4; ++c) {
            float4 hv4 = *(const float4*)(sh_h + c*512 + k*4);
            pr += w[0][c].x*hv4.x + w[0][c].y*hv4.y + w[0][c].z*hv4.z + w[0][c].w*hv4.w;
            pz += w[1][c].x*hv4.x + w[1][c].y*hv4.y + w[1][c].z*hv4.z + w[1][c].w*hv4.w;
            pn += w[2][c].x*hv4.x + w[2][c].y*hv4.y + w[2][c].z*hv4.z + w[2][c].w*hv4.w;
        }
        #pragma unroll
        for (int off = 32; off >= 1; off >>= 1) {
            pr += __shfl_down(pr, off, 64);
            pz += __shfl_down(pz, off, 64);
            pn += __shfl_down(pn, off, 64);
        }
        if (lane == 0) { sred[wv][0] = pr; sred[wv][1] = pz; sred[wv][2] = pn; }

        // wave 0: finish pred reduction -> pk for this step
        if (wv == 0) {
            float s = (lane < 16) ? swp[lane] : 0.f;
            s += __shfl_down(s, 8, 64);
            s += __shfl_down(s, 4, 64);
            s += __shfl_down(s, 2, 64);
            s += __shfl_down(s, 1, 64);
            if (lane == 0) {
                float pred = s + bo;                 // pred_{t-1}
                float pk;
                if (t == 0) pk = s_pkd[0];
                else        pk = (s_tf[t] == 1) ? pred : s_pkd[t];
                sPk = pk;
                if (b == 0 && t > 0) out[t] = pred;  // outputs[t] = pred_{t-1}
            }
        }
        __syncthreads();                         // B2: sred + sPk ready

        // ---- leaders: gates + publish tagged h pair ----
        if (k == 0) {
            float dotr = sred[2*g][0] + sred[2*g+1][0];
            float dotz = sred[2*g][1] + sred[2*g+1][1];
            float dotn = sred[2*g][2] + sred[2*g+1][2];
            float pk = sPk;
            float tp = s_tp[t];
            float gr  = apk_r*pk + atp_r*tp + cvt_r + dotr + br;
            float gz  = apk_z*pk + atp_z*tp + cvt_z + dotz + bz;
            float gin = apk_n*pk + atp_n*tp + cvt_n;
            float r = 1.0f / (1.0f + expf(-gr));
            float z = 1.0f / (1.0f + expf(-gz));
            float n = tanhf(gin + r*(dotn + bn));
            float hvnew = (1.0f - z)*n + z*hprev;
            hprev = hvnew;
            union { float f; unsigned u; } cv; cv.f = hvnew;
            unsigned long long pkt =
                ((unsigned long long)(unsigned)(t + 1) << 32) | (unsigned long long)cv.u;
            __hip_atomic_store(hp + pw_*Hdim + j, pkt,
                               __ATOMIC_RELAXED, __HIP_MEMORY_SCOPE_AGENT);
        }
    }

    // ---- final prediction -> out[255] = W_out . h_255 + b_out ----
    if (b == 0) {
        unsigned long long* hin = hp + ((Ldim - 1) & 1) * Hdim;
        unsigned long long p0, p1;
        for (;;) {
            p0 = __hip_atomic_load(hin + i0,     __ATOMIC_RELAXED, __HIP_MEMORY_SCOPE_AGENT);
            p1 = __hip_atomic_load(hin + i0 + 1, __ATOMIC_RELAXED, __HIP_MEMORY_SCOPE_AGENT);
            if ((int)(p0 >> 32) >= Ldim - 1 && (int)(p1 >> 32) >= Ldim - 1) break;
        }
        union { unsigned u; float f; } c0, c1;
        c0.u = (unsigned)p0; c1.u = (unsigned)p1;
        float wpart = wo0*c0.f + wo1*c1.f;
        #pragma unroll
        for (int off = 32; off >= 1; off >>= 1) wpart += __shfl_down(wpart, off, 64);
        if (lane == 0) swp[wv] = wpart;
        __syncthreads();
        if (wv == 0) {
            float s = (lane < 16) ? swp[lane] : 0.f;
            s += __shfl_down(s, 8, 64);
            s += __shfl_down(s, 4, 64);
            s += __shfl_down(s, 2, 64);
            s += __shfl_down(s, 1, 64);
            if (lane == 0) out[Ldim - 1] = s + bo;
        }
    }
}

extern "C" void kernel_launch(void* const* d_in, const int* in_sizes, int n_in,
                              void* d_out, int out_size, void* d_ws, size_t ws_size,
                              hipStream_t stream)
{
    const float* tps    = (const float*)d_in[0];   // timepoints (256,1)
    const float* pkdata = (const float*)d_in[1];   // pk_data (256,1)
    // d_in[2] = input_len (unused, static 256)
    const int*   pat    = (const int*)  d_in[3];   // emb_patient
    const float* route  = (const float*)d_in[4];   // drug_route (1,)
    const float* dose   = (const float*)d_in[5];   // dose (1,)
    const float* smiles = (const float*)d_in[6];   // (1, 2048)
    const int*   tfm    = (const int*)  d_in[7];   // tf_mask (256,)
    const float* emb    = (const float*)d_in[8];   // emb_table (8,3)
    const float* Wp     = (const float*)d_in[9];   // W_pre (2048,7)
    const float* bpre   = (const float*)d_in[10];  // b_pre (2048,)
    const float* Wih    = (const float*)d_in[11];  // W_ih (6144,2048)
    const float* Whh    = (const float*)d_in[12];  // W_hh (6144,2048)
    const float* bih    = (const float*)d_in[13];  // b_ih (6144,)
    const float* bhh    = (const float*)d_in[14];  // b_hh (6144,)
    const float* Wout   = (const float*)d_in[15];  // W_out (1,2048)
    const float* bout   = (const float*)d_in[16];  // b_out (1,)
    float* out = (float*)d_out;
    float* ws  = (float*)d_ws;

    hipLaunchKernelGGL(prep1, dim3(1), dim3(256), 0, stream,
                       Wp, bpre, dose, route, emb, pat, smiles, pkdata, ws, out);
    hipLaunchKernelGGL(prep2, dim3(1536), dim3(256), 0, stream,
                       Wih, Wp, bih, ws);
    hipLaunchKernelGGL(gru_main, dim3(NBLK), dim3(TPB), 0, stream,
                       Whh, bhh, Wout, bout, tps, pkdata, tfm, smiles, ws, out);
}

// Round 4
// 1871.072 us; speedup vs baseline: 1.9196x; 1.1070x over previous
//
#include <hip/hip_runtime.h>
#include <math.h>

#define Hdim 2048
#define Ldim 256
#define NBLK 256
#define TPB  1024
#define JPB  8      // h-elements per block (Hdim / NBLK)

// workspace layout (float offsets)
#define WS_U    0        // 2048 : u[k] = Wp[:,2:]*consts + b_pre
#define WS_H    2048     // 2*2048 : double-buffered plain h
#define WS_TAG  6144     // 256 ints : per-producer-block step tags (16 lines)
#define WS_APK  6400     // 6144 : pk coefficient  (W_ih @ Wp[:,0])
#define WS_ATP  12544    // 6144 : tp coefficient  (W_ih @ Wp[:,1])
#define WS_CVT  18688    // 6144 : const part of gi (W_ih @ u + b_ih)

// ---------------- prep 1: u vector, h0, tag reset, out[0] -------------------
__global__ void prep1(const float* __restrict__ Wp, const float* __restrict__ bpre,
                      const float* __restrict__ dose, const float* __restrict__ route,
                      const float* __restrict__ emb, const int* __restrict__ pat,
                      const float* __restrict__ smiles, const float* __restrict__ pkdata,
                      float* __restrict__ ws, float* __restrict__ out)
{
    int tid = threadIdx.x;
    float d = dose[0], rt = route[0];
    int p = pat[0];
    float e0 = emb[p*3+0], e1 = emb[p*3+1], e2 = emb[p*3+2];
    for (int i = tid; i < Hdim; i += 256) {
        const float* w = Wp + i*7;
        ws[WS_U + i] = d*w[2] + e0*w[3] + e1*w[4] + e2*w[5] + rt*w[6] + bpre[i];
        ws[WS_H + i] = smiles[i];          // parity 0 = h0
    }
    ((int*)(ws + WS_TAG))[tid] = 0;        // tags start at 0 (h0 published)
    if (tid == 0) out[0] = pkdata[0];
}

// ---------------- prep 2: fold W_ih through W_pre (3 matvecs) ---------------
__global__ void prep2(const float* __restrict__ Wih, const float* __restrict__ Wp,
                      const float* __restrict__ bih, float* __restrict__ ws)
{
    int row  = blockIdx.x*4 + (threadIdx.x >> 6);
    int lane = threadIdx.x & 63;
    const float* wr = Wih + (size_t)row * Hdim;
    const float* u  = ws + WS_U;
    float s0 = 0.f, s1 = 0.f, s2 = 0.f;
    #pragma unroll
    for (int c = 0; c < 8; ++c) {
        int col = c*256 + lane*4;
        float4 wv = *(const float4*)(wr + col);
        float4 uv = *(const float4*)(u + col);
        s0 += wv.x*Wp[(col+0)*7+0] + wv.y*Wp[(col+1)*7+0]
            + wv.z*Wp[(col+2)*7+0] + wv.w*Wp[(col+3)*7+0];
        s1 += wv.x*Wp[(col+0)*7+1] + wv.y*Wp[(col+1)*7+1]
            + wv.z*Wp[(col+2)*7+1] + wv.w*Wp[(col+3)*7+1];
        s2 += wv.x*uv.x + wv.y*uv.y + wv.z*uv.z + wv.w*uv.w;
    }
    #pragma unroll
    for (int off = 32; off >= 1; off >>= 1) {
        s0 += __shfl_down(s0, off, 64);
        s1 += __shfl_down(s1, off, 64);
        s2 += __shfl_down(s2, off, 64);
    }
    if (lane == 0) {
        ws[WS_APK + row] = s0;
        ws[WS_ATP + row] = s1;
        ws[WS_CVT + row] = s2 + bih[row];
    }
}

// ---------------- main persistent kernel ------------------------------------
// 256 blocks x 1024 threads, 1 block/CU. Block b owns h[j], j = b*8..b*8+7.
// Sync: 256 per-producer tags (1 line / 16 producers); payload loaded once.
// Producer: wave0 lanes0-7 compute gates, 1 coalesced store, s_waitcnt(0),
// tag store. Tag certifies the whole block is done READING h_t, so the
// parity double-buffer cannot be overwritten early (2-phase protocol).
__global__ __launch_bounds__(TPB, 4) void gru_main(
    const float* __restrict__ Whh, const float* __restrict__ bhh,
    const float* __restrict__ Wout, const float* __restrict__ bout,
    const float* __restrict__ tps,  const float* __restrict__ pkdata,
    const int*   __restrict__ tf,   const float* __restrict__ smiles,
    float* __restrict__ ws, float* __restrict__ out)
{
    const int b    = blockIdx.x;
    const int tid  = threadIdx.x;
    const int k    = tid & 127;     // column group within j (dots)
    const int g    = tid >> 7;      // which j this thread's dot serves
    const int wv   = tid >> 6;      // wave id 0..15
    const int lane = tid & 63;
    const int j    = b*JPB + g;

    __shared__ float sh_h[Hdim];
    __shared__ float sred[16][3];
    __shared__ float swp[2][16];    // parity double-buffered (run-ahead safe)
    __shared__ float s_tp[Ldim];
    __shared__ float s_pkd[Ldim];
    __shared__ int   s_tf[Ldim];

    float* hbuf = ws + WS_H;
    int*   tagp = (int*)(ws + WS_TAG);

    for (int i = tid; i < Ldim; i += TPB) {
        s_tp[i]  = tps[i];
        s_pkd[i] = pkdata[i];
        s_tf[i]  = tf[i];
    }

    // W_hh rows -> registers (48 VGPRs), coalesced float4 loads
    float4 w[3][4];
    #pragma unroll
    for (int r = 0; r < 3; ++r) {
        const float* base = Whh + (size_t)(j + r*Hdim) * Hdim;
        #pragma unroll
        for (int c = 0; c < 4; ++c)
            w[r][c] = *(const float4*)(base + c*512 + k*4);
    }

    // per-thread W_out slice
    const int i0 = tid * 2;
    const float wo0 = Wout[i0], wo1 = Wout[i0 + 1];

    // wave0 lanes 0-7: per-lane gate constants for j = b*8+lane
    float apk_r=0, apk_z=0, apk_n=0, atp_r=0, atp_z=0, atp_n=0,
          cvt_r=0, cvt_z=0, cvt_n=0, br=0, bz=0, bn=0, hprev=0;
    if (wv == 0 && lane < JPB) {
        int jj = b*JPB + lane;
        apk_r = ws[WS_APK + jj]; apk_z = ws[WS_APK + jj + Hdim]; apk_n = ws[WS_APK + jj + 2*Hdim];
        atp_r = ws[WS_ATP + jj]; atp_z = ws[WS_ATP + jj + Hdim]; atp_n = ws[WS_ATP + jj + 2*Hdim];
        cvt_r = ws[WS_CVT + jj]; cvt_z = ws[WS_CVT + jj + Hdim]; cvt_n = ws[WS_CVT + jj + 2*Hdim];
        br = bhh[jj]; bz = bhh[jj + Hdim]; bn = bhh[jj + 2*Hdim];
        hprev = smiles[jj];
    }
    const float bo = bout[0];
    __syncthreads();

    for (int t = 0; t < Ldim; ++t) {
        const int pr_ = t & 1;

        // ---- poll readiness: one 64B tag line per wave ----
        {
            const int* tpp = tagp + wv*16 + (lane & 15);
            for (;;) {
                int tv = __hip_atomic_load(tpp, __ATOMIC_RELAXED, __HIP_MEMORY_SCOPE_AGENT);
                if (__all(tv >= t)) break;
            }
        }

        // ---- one-shot payload load: my 2 h values (8B, coherent) ----
        unsigned long long dv = __hip_atomic_load(
            (const unsigned long long*)(hbuf + pr_*Hdim + i0),
            __ATOMIC_RELAXED, __HIP_MEMORY_SCOPE_AGENT);
        float h0 = __uint_as_float((unsigned)dv);
        float h1 = __uint_as_float((unsigned)(dv >> 32));
        sh_h[i0]     = h0;
        sh_h[i0 + 1] = h1;

        // local pred partial (pred_{t-1} = W_out . h_t + b_out)
        float wpart = wo0*h0 + wo1*h1;
        #pragma unroll
        for (int off = 32; off >= 1; off >>= 1) wpart += __shfl_down(wpart, off, 64);
        if (lane == 0) swp[pr_][wv] = wpart;
        __syncthreads();                         // B1: h staged

        // ---- dots: 3 gate rows x 16 columns per thread, from LDS ----
        float prd = 0.f, pzd = 0.f, pnd = 0.f;
        #pragma unroll
        for (int c = 0; c < 4; ++c) {
            float4 hv4 = *(const float4*)(sh_h + c*512 + k*4);
            prd += w[0][c].x*hv4.x + w[0][c].y*hv4.y + w[0][c].z*hv4.z + w[0][c].w*hv4.w;
            pzd += w[1][c].x*hv4.x + w[1][c].y*hv4.y + w[1][c].z*hv4.z + w[1][c].w*hv4.w;
            pnd += w[2][c].x*hv4.x + w[2][c].y*hv4.y + w[2][c].z*hv4.z + w[2][c].w*hv4.w;
        }
        #pragma unroll
        for (int off = 32; off >= 1; off >>= 1) {
            prd += __shfl_down(prd, off, 64);
            pzd += __shfl_down(pzd, off, 64);
            pnd += __shfl_down(pnd, off, 64);
        }
        if (lane == 0) { sred[wv][0] = prd; sred[wv][1] = pzd; sred[wv][2] = pnd; }
        __syncthreads();                         // B2: sred ready

        // ---- wave 0: pred, pk, gates, publish; other waves race ahead ----
        if (wv == 0) {
            float s = (lane < 16) ? swp[pr_][lane] : 0.f;
            s += __shfl_down(s, 8, 64);
            s += __shfl_down(s, 4, 64);
            s += __shfl_down(s, 2, 64);
            s += __shfl_down(s, 1, 64);
            float pred = __shfl(s, 0) + bo;      // pred_{t-1}
            float pk = (t == 0) ? s_pkd[0] : ((s_tf[t] == 1) ? pred : s_pkd[t]);
            if (b == 0 && lane == 0 && t > 0) out[t] = pred;
            if (t < Ldim - 1) {
                if (lane < JPB) {
                    float dotr = sred[2*lane][0] + sred[2*lane+1][0];
                    float dotz = sred[2*lane][1] + sred[2*lane+1][1];
                    float dotn = sred[2*lane][2] + sred[2*lane+1][2];
                    float tp  = s_tp[t];
                    float gr  = apk_r*pk + atp_r*tp + cvt_r + dotr + br;
                    float gz  = apk_z*pk + atp_z*tp + cvt_z + dotz + bz;
                    float gin = apk_n*pk + atp_n*tp + cvt_n;
                    float r = 1.0f / (1.0f + expf(-gr));
                    float z = 1.0f / (1.0f + expf(-gz));
                    float n = tanhf(gin + r*(dotn + bn));
                    float hvnew = (1.0f - z)*n + z*hprev;
                    hprev = hvnew;
                    __hip_atomic_store(hbuf + (pr_^1)*Hdim + b*JPB + lane, hvnew,
                                       __ATOMIC_RELAXED, __HIP_MEMORY_SCOPE_AGENT);
                }
                __builtin_amdgcn_s_waitcnt(0);   // drain the wave's h stores
                if (lane == 0)
                    __hip_atomic_store(tagp + b, t + 1,
                                       __ATOMIC_RELAXED, __HIP_MEMORY_SCOPE_AGENT);
            }
        }
    }
}

extern "C" void kernel_launch(void* const* d_in, const int* in_sizes, int n_in,
                              void* d_out, int out_size, void* d_ws, size_t ws_size,
                              hipStream_t stream)
{
    const float* tps    = (const float*)d_in[0];   // timepoints (256,1)
    const float* pkdata = (const float*)d_in[1];   // pk_data (256,1)
    // d_in[2] = input_len (unused, static 256)
    const int*   pat    = (const int*)  d_in[3];   // emb_patient
    const float* route  = (const float*)d_in[4];   // drug_route (1,)
    const float* dose   = (const float*)d_in[5];   // dose (1,)
    const float* smiles = (const float*)d_in[6];   // (1, 2048)
    const int*   tfm    = (const int*)  d_in[7];   // tf_mask (256,)
    const float* emb    = (const float*)d_in[8];   // emb_table (8,3)
    const float* Wp     = (const float*)d_in[9];   // W_pre (2048,7)
    const float* bpre   = (const float*)d_in[10];  // b_pre (2048,)
    const float* Wih    = (const float*)d_in[11];  // W_ih (6144,2048)
    const float* Whh    = (const float*)d_in[12];  // W_hh (6144,2048)
    const float* bih    = (const float*)d_in[13];  // b_ih (6144,)
    const float* bhh    = (const float*)d_in[14];  // b_hh (6144,)
    const float* Wout   = (const float*)d_in[15];  // W_out (1,2048)
    const float* bout   = (const float*)d_in[16];  // b_out (1,)
    float* out = (float*)d_out;
    float* ws  = (float*)d_ws;

    hipLaunchKernelGGL(prep1, dim3(1), dim3(256), 0, stream,
                       Wp, bpre, dose, route, emb, pat, smiles, pkdata, ws, out);
    hipLaunchKernelGGL(prep2, dim3(1536), dim3(256), 0, stream,
                       Wih, Wp, bih, ws);
    hipLaunchKernelGGL(gru_main, dim3(NBLK), dim3(TPB), 0, stream,
                       Whh, bhh, Wout, bout, tps, pkdata, tfm, smiles, ws, out);
}

// Round 5
// 1104.391 us; speedup vs baseline: 3.2523x; 1.6942x over previous
//
#include <hip/hip_runtime.h>
#include <math.h>

#define Hdim 2048
#define Ldim 256
#define NBLK 256
#define TPB  1024
#define JPB  8      // h-elements per block (Hdim / NBLK)

typedef unsigned long long u64;

// workspace layout (float offsets)
#define WS_U    0        // 2048 : u[k] = Wp[:,2:]*consts + b_pre
#define WS_HP   2048     // 8192 : 2 parities x 2048 (tag,value) u64 pairs
#define WS_APK  10240    // 6144 : pk coefficient  (W_ih @ Wp[:,0])
#define WS_ATP  16384    // 6144 : tp coefficient  (W_ih @ Wp[:,1])
#define WS_CVT  22528    // 6144 : const part of gi (W_ih @ u + b_ih)

// ---------------- prep 1: u vector, tagged h0 pairs, out[0] -----------------
__global__ void prep1(const float* __restrict__ Wp, const float* __restrict__ bpre,
                      const float* __restrict__ dose, const float* __restrict__ route,
                      const float* __restrict__ emb, const int* __restrict__ pat,
                      const float* __restrict__ smiles, const float* __restrict__ pkdata,
                      float* __restrict__ ws, float* __restrict__ out)
{
    int tid = threadIdx.x;
    float d = dose[0], rt = route[0];
    int p = pat[0];
    float e0 = emb[p*3+0], e1 = emb[p*3+1], e2 = emb[p*3+2];
    u64* hp0 = (u64*)(ws + WS_HP);          // parity 0
    for (int i = tid; i < Hdim; i += 256) {
        const float* w = Wp + i*7;
        ws[WS_U + i] = d*w[2] + e0*w[3] + e1*w[4] + e2*w[5] + rt*w[6] + bpre[i];
        union { float f; unsigned u; } cv; cv.f = smiles[i];
        hp0[i] = (u64)cv.u;                 // tag 0 (high word), h0 (low word)
    }
    if (tid == 0) out[0] = pkdata[0];
    // parity 1 is left poisoned (0xAA... -> tag negative as int) = "not ready"
}

// ---------------- prep 2: fold W_ih through W_pre (3 matvecs) ---------------
__global__ void prep2(const float* __restrict__ Wih, const float* __restrict__ Wp,
                      const float* __restrict__ bih, float* __restrict__ ws)
{
    int row  = blockIdx.x*4 + (threadIdx.x >> 6);
    int lane = threadIdx.x & 63;
    const float* wr = Wih + (size_t)row * Hdim;
    const float* u  = ws + WS_U;
    float s0 = 0.f, s1 = 0.f, s2 = 0.f;
    #pragma unroll
    for (int c = 0; c < 8; ++c) {
        int col = c*256 + lane*4;
        float4 wv = *(const float4*)(wr + col);
        float4 uv = *(const float4*)(u + col);
        s0 += wv.x*Wp[(col+0)*7+0] + wv.y*Wp[(col+1)*7+0]
            + wv.z*Wp[(col+2)*7+0] + wv.w*Wp[(col+3)*7+0];
        s1 += wv.x*Wp[(col+0)*7+1] + wv.y*Wp[(col+1)*7+1]
            + wv.z*Wp[(col+2)*7+1] + wv.w*Wp[(col+3)*7+1];
        s2 += wv.x*uv.x + wv.y*uv.y + wv.z*uv.z + wv.w*uv.w;
    }
    #pragma unroll
    for (int off = 32; off >= 1; off >>= 1) {
        s0 += __shfl_down(s0, off, 64);
        s1 += __shfl_down(s1, off, 64);
        s2 += __shfl_down(s2, off, 64);
    }
    if (lane == 0) {
        ws[WS_APK + row] = s0;
        ws[WS_ATP + row] = s1;
        ws[WS_CVT + row] = s2 + bih[row];
    }
}

// ---------------- main persistent kernel ------------------------------------
// 256 blocks x 1024 threads, 1 block/CU. Block b owns h[j], j = b*8..b*8+7.
// Minimum-hop sync: tag travels WITH value in 8B pairs; producer wave0 emits
// all 8 pairs as ONE coalesced 64B fire-and-forget store (no ack, no flag).
// 2-phase safety: wave0 publishes after B2; a block reaching step t+1 proves
// every block passed B1 of step t-1, so parity overwrite is race-free.
__global__ __launch_bounds__(TPB, 4) void gru_main(
    const float* __restrict__ Whh, const float* __restrict__ bhh,
    const float* __restrict__ Wout, const float* __restrict__ bout,
    const float* __restrict__ tps,  const float* __restrict__ pkdata,
    const int*   __restrict__ tf,   const float* __restrict__ smiles,
    float* __restrict__ ws, float* __restrict__ out)
{
    const int b    = blockIdx.x;
    const int tid  = threadIdx.x;
    const int k    = tid & 127;     // column group within j (dots)
    const int g    = tid >> 7;      // which j this thread's dot serves
    const int wv   = tid >> 6;      // wave id 0..15
    const int lane = tid & 63;
    const int j    = b*JPB + g;

    __shared__ float sh_h[Hdim];
    __shared__ float sred[16][3];
    __shared__ float swp[2][16];
    __shared__ float s_tp[Ldim];
    __shared__ float s_pkd[Ldim];
    __shared__ int   s_tf[Ldim];

    u64* hp = (u64*)(ws + WS_HP);

    for (int i = tid; i < Ldim; i += TPB) {
        s_tp[i]  = tps[i];
        s_pkd[i] = pkdata[i];
        s_tf[i]  = tf[i];
    }

    // W_hh rows -> registers (48 VGPRs), coalesced float4 loads
    float4 w[3][4];
    #pragma unroll
    for (int r = 0; r < 3; ++r) {
        const float* base = Whh + (size_t)(j + r*Hdim) * Hdim;
        #pragma unroll
        for (int c = 0; c < 4; ++c)
            w[r][c] = *(const float4*)(base + c*512 + k*4);
    }

    // per-thread W_out slice
    const int i0 = tid * 2;
    const float wo0 = Wout[i0], wo1 = Wout[i0 + 1];

    // wave0 lanes 0-7: per-lane gate constants for j = b*8+lane
    float apk_r=0, apk_z=0, apk_n=0, atp_r=0, atp_z=0, atp_n=0,
          cvt_r=0, cvt_z=0, cvt_n=0, br=0, bz=0, bn=0, hprev=0;
    if (wv == 0 && lane < JPB) {
        int jj = b*JPB + lane;
        apk_r = ws[WS_APK + jj]; apk_z = ws[WS_APK + jj + Hdim]; apk_n = ws[WS_APK + jj + 2*Hdim];
        atp_r = ws[WS_ATP + jj]; atp_z = ws[WS_ATP + jj + Hdim]; atp_n = ws[WS_ATP + jj + 2*Hdim];
        cvt_r = ws[WS_CVT + jj]; cvt_z = ws[WS_CVT + jj + Hdim]; cvt_n = ws[WS_CVT + jj + 2*Hdim];
        br = bhh[jj]; bz = bhh[jj + Hdim]; bn = bhh[jj + 2*Hdim];
        hprev = smiles[jj];
    }
    const float bo = bout[0];
    __syncthreads();

    for (int t = 0; t < Ldim - 1; ++t) {
        const int pr_ = t & 1;
        const u64* hin = hp + pr_ * Hdim;

        // ---- poll: tag+payload in ONE load pair (detect == data ready) ----
        u64 p0, p1;
        for (;;) {
            p0 = __hip_atomic_load(hin + i0,     __ATOMIC_RELAXED, __HIP_MEMORY_SCOPE_AGENT);
            p1 = __hip_atomic_load(hin + i0 + 1, __ATOMIC_RELAXED, __HIP_MEMORY_SCOPE_AGENT);
            if ((int)(p0 >> 32) >= t && (int)(p1 >> 32) >= t) break;
        }
        float h0 = __uint_as_float((unsigned)p0);
        float h1 = __uint_as_float((unsigned)p1);
        sh_h[i0]     = h0;
        sh_h[i0 + 1] = h1;

        // local pred partial (pred_{t-1} = W_out . h_t + b_out)
        float wpart = wo0*h0 + wo1*h1;
        #pragma unroll
        for (int off = 32; off >= 1; off >>= 1) wpart += __shfl_down(wpart, off, 64);
        if (lane == 0) swp[pr_][wv] = wpart;
        __syncthreads();                         // B1: h staged

        // ---- dots: 3 gate rows x 16 columns per thread, from LDS ----
        float prd = 0.f, pzd = 0.f, pnd = 0.f;
        #pragma unroll
        for (int c = 0; c < 4; ++c) {
            float4 hv4 = *(const float4*)(sh_h + c*512 + k*4);
            prd += w[0][c].x*hv4.x + w[0][c].y*hv4.y + w[0][c].z*hv4.z + w[0][c].w*hv4.w;
            pzd += w[1][c].x*hv4.x + w[1][c].y*hv4.y + w[1][c].z*hv4.z + w[1][c].w*hv4.w;
            pnd += w[2][c].x*hv4.x + w[2][c].y*hv4.y + w[2][c].z*hv4.z + w[2][c].w*hv4.w;
        }
        #pragma unroll
        for (int off = 32; off >= 1; off >>= 1) {
            prd += __shfl_down(prd, off, 64);
            pzd += __shfl_down(pzd, off, 64);
            pnd += __shfl_down(pnd, off, 64);
        }
        if (lane == 0) { sred[wv][0] = prd; sred[wv][1] = pzd; sred[wv][2] = pnd; }
        __syncthreads();                         // B2: sred ready

        // ---- wave 0: pred, pk, gates, ONE coalesced tagged publish ----
        if (wv == 0) {
            float s = (lane < 16) ? swp[pr_][lane] : 0.f;
            s += __shfl_down(s, 8, 64);
            s += __shfl_down(s, 4, 64);
            s += __shfl_down(s, 2, 64);
            s += __shfl_down(s, 1, 64);
            float pred = __shfl(s, 0) + bo;      // pred_{t-1}
            float pk = (t == 0) ? s_pkd[0] : ((s_tf[t] == 1) ? pred : s_pkd[t]);
            if (b == 0 && lane == 0 && t > 0) out[t] = pred;
            if (lane < JPB) {
                float dotr = sred[2*lane][0] + sred[2*lane+1][0];
                float dotz = sred[2*lane][1] + sred[2*lane+1][1];
                float dotn = sred[2*lane][2] + sred[2*lane+1][2];
                float tp  = s_tp[t];
                float gr  = apk_r*pk + atp_r*tp + cvt_r + dotr + br;
                float gz  = apk_z*pk + atp_z*tp + cvt_z + dotz + bz;
                float gin = apk_n*pk + atp_n*tp + cvt_n;
                float r = 1.0f / (1.0f + expf(-gr));
                float z = 1.0f / (1.0f + expf(-gz));
                float n = tanhf(gin + r*(dotn + bn));
                float hvnew = (1.0f - z)*n + z*hprev;
                hprev = hvnew;
                u64 pkt = ((u64)(unsigned)(t + 1) << 32) | (u64)__float_as_uint(hvnew);
                __hip_atomic_store(hp + (pr_^1)*Hdim + b*JPB + lane, pkt,
                                   __ATOMIC_RELAXED, __HIP_MEMORY_SCOPE_AGENT);
            }
        }
    }

    // ---- final: only block 0 polls h_255 and writes out[255] ----
    if (b == 0) {
        const u64* hin = hp + ((Ldim - 1) & 1) * Hdim;
        u64 p0, p1;
        for (;;) {
            p0 = __hip_atomic_load(hin + i0,     __ATOMIC_RELAXED, __HIP_MEMORY_SCOPE_AGENT);
            p1 = __hip_atomic_load(hin + i0 + 1, __ATOMIC_RELAXED, __HIP_MEMORY_SCOPE_AGENT);
            if ((int)(p0 >> 32) >= Ldim - 1 && (int)(p1 >> 32) >= Ldim - 1) break;
        }
        float h0 = __uint_as_float((unsigned)p0);
        float h1 = __uint_as_float((unsigned)p1);
        float wpart = wo0*h0 + wo1*h1;
        #pragma unroll
        for (int off = 32; off >= 1; off >>= 1) wpart += __shfl_down(wpart, off, 64);
        if (lane == 0) swp[1][wv] = wpart;
        __syncthreads();
        if (wv == 0) {
            float s = (lane < 16) ? swp[1][lane] : 0.f;
            s += __shfl_down(s, 8, 64);
            s += __shfl_down(s, 4, 64);
            s += __shfl_down(s, 2, 64);
            s += __shfl_down(s, 1, 64);
            if (lane == 0) out[Ldim - 1] = s + bo;
        }
    }
}

extern "C" void kernel_launch(void* const* d_in, const int* in_sizes, int n_in,
                              void* d_out, int out_size, void* d_ws, size_t ws_size,
                              hipStream_t stream)
{
    const float* tps    = (const float*)d_in[0];   // timepoints (256,1)
    const float* pkdata = (const float*)d_in[1];   // pk_data (256,1)
    // d_in[2] = input_len (unused, static 256)
    const int*   pat    = (const int*)  d_in[3];   // emb_patient
    const float* route  = (const float*)d_in[4];   // drug_route (1,)
    const float* dose   = (const float*)d_in[5];   // dose (1,)
    const float* smiles = (const float*)d_in[6];   // (1, 2048)
    const int*   tfm    = (const int*)  d_in[7];   // tf_mask (256,)
    const float* emb    = (const float*)d_in[8];   // emb_table (8,3)
    const float* Wp     = (const float*)d_in[9];   // W_pre (2048,7)
    const float* bpre   = (const float*)d_in[10];  // b_pre (2048,)
    const float* Wih    = (const float*)d_in[11];  // W_ih (6144,2048)
    const float* Whh    = (const float*)d_in[12];  // W_hh (6144,2048)
    const float* bih    = (const float*)d_in[13];  // b_ih (6144,)
    const float* bhh    = (const float*)d_in[14];  // b_hh (6144,)
    const float* Wout   = (const float*)d_in[15];  // W_out (1,2048)
    const float* bout   = (const float*)d_in[16];  // b_out (1,)
    float* out = (float*)d_out;
    float* ws  = (float*)d_ws;

    hipLaunchKernelGGL(prep1, dim3(1), dim3(256), 0, stream,
                       Wp, bpre, dose, route, emb, pat, smiles, pkdata, ws, out);
    hipLaunchKernelGGL(prep2, dim3(1536), dim3(256), 0, stream,
                       Wih, Wp, bih, ws);
    hipLaunchKernelGGL(gru_main, dim3(NBLK), dim3(TPB), 0, stream,
                       Whh, bhh, Wout, bout, tps, pkdata, tfm, smiles, ws, out);
}